// Round 1
// baseline (268.544 us; speedup 1.0000x reference)
//
#include <hip/hip_runtime.h>

// DVQ bottleneck: B=8, N=4096, D=1024, S=4, K=16, d=256, BETA=0.25
// Outputs (flat fp32 in d_out): z[8*4096*1024], ids_packed[32768] (as float),
// vq_total[1].
//
// R6: attack the LDS-broadcast instruction rate (theory: per-CU LDS pipe was
// ~45% serialized on 512 broadcast ds_read_b128 per wave-task, 2 fp64 FMA per
// read, while VALU sat at 14.5%). Changes vs R5:
//   (a) T=2 token blocking: lane owns tokens {lane, lane+64}; block = 128
//       tokens x 1 segment; each codebook broadcast feeds 8 FMAs.
//   (b) codebook staged in LDS as fp32 (16 KB) + exact v_cvt_f64_f32 in
//       registers -> 1 ds_read_b128 delivers 4 codebook values.
//   Net: LDS reads per useful FMA drop 4x. Distance math stays full fp64
//   (cvt is exact), argmin/tie-break identical to R5.
// Cross-wave partial reduce runs in two rounds (A: tokens lane, B: lane+64)
// reusing one 26.1 KB arena that also held the fp32 codebook during compute.

#define D_FULL 1024
#define SEG 4
#define DSEG 256
#define KC 16

// Prep (64 blocks x 256): fp64 ||c||^2 per (s,k), zero ids_out + loss
// (d_out/d_ws poisoned 0xAA before every timed launch).
__global__ __launch_bounds__(256) void dvq_prep(const float* __restrict__ cb,
                                                double* __restrict__ c2d,
                                                float* __restrict__ ids_out,
                                                float* __restrict__ loss_out) {
    __shared__ double ws[4];
    const int b = blockIdx.x;    // 0..63 == (s,k) pair
    const int t = threadIdx.x;
    const int lane = t & 63;
    const int w = t >> 6;

    ids_out[b * 512 + t] = 0.0f;
    ids_out[b * 512 + 256 + t] = 0.0f;
    if (b == 0 && t == 0) *loss_out = 0.0f;

    double v = (double)cb[b * 256 + t];
    double sq = v * v;
#pragma unroll
    for (int off = 32; off > 0; off >>= 1)
        sq += __shfl_down(sq, off, 64);
    if (lane == 0) ws[w] = sq;
    __syncthreads();
    if (t == 0) c2d[b] = ws[0] + ws[1] + ws[2] + ws[3];
}

__global__ __launch_bounds__(256, 4) void dvq_main(const float* __restrict__ h,
                                                   const float* __restrict__ cb,
                                                   const double* __restrict__ c2d,
                                                   float* __restrict__ z_out,
                                                   float* __restrict__ ids_out,
                                                   float* __restrict__ loss_out) {
    // arena phase 1: fp32 codebook slice (16 KB of it).
    // arena phase 2: cross-wave partial buffer [3][64][17] doubles = 26112 B.
    __shared__ __align__(16) double arena[3 * 64 * (KC + 1)];
    __shared__ int ids_lds[128];

    const int i = threadIdx.x;
    const int lane = i & 63;                           // token within half-block
    const int w = i >> 6;                              // wave id == d-chunk
    const int ch = __builtin_amdgcn_readfirstlane(w);  // wave-uniform SGPR

    const int s = blockIdx.x & 3;                      // segment
    const long tok_base = (long)(blockIdx.x >> 2) * 128;
    const long tokA = tok_base + lane;
    const long tokB = tokA + 64;

    float* cbl = reinterpret_cast<float*>(arena);

    // ---- Stage fp32 codebook slice (16 KB) straight from cb (L2-resident) ----
    {
        const float4* src = reinterpret_cast<const float4*>(cb + s * (KC * DSEG));
        float4* dst = reinterpret_cast<float4*>(cbl);
#pragma unroll
        for (int jj = 0; jj < 16; ++jj)
            dst[jj * 256 + i] = src[jj * 256 + i];
    }
    __syncthreads();

    // ---- Phase 1: fp64 partial dots over this wave's 64-float chunk for
    // TWO tokens per lane. Codebook via wave-uniform b128 broadcast (4 fp32
    // per read, exact cvt to fp64). ----
    const float4* zpA = (const float4*)(h + tokA * D_FULL + (long)s * DSEG + ch * 64);
    const float4* zpB = (const float4*)(h + tokB * D_FULL + (long)s * DSEG + ch * 64);
    const float* cbs = cbl + ch * 64;  // LDS, wave-uniform

    double dotA[KC], dotB[KC];
#pragma unroll
    for (int k = 0; k < KC; ++k) { dotA[k] = 0.0; dotB[k] = 0.0; }
    double zeA = 0.0, zeB = 0.0;

#pragma unroll 4
    for (int j = 0; j < 16; ++j) {
        float4 a4 = zpA[j];
        float4 b4 = zpB[j];
        double a0 = (double)a4.x, a1 = (double)a4.y;
        double a2 = (double)a4.z, a3 = (double)a4.w;
        double b0 = (double)b4.x, b1 = (double)b4.y;
        double b2 = (double)b4.z, b3 = (double)b4.w;
        zeA = fma(a0, a0, zeA); zeA = fma(a1, a1, zeA);
        zeA = fma(a2, a2, zeA); zeA = fma(a3, a3, zeA);
        zeB = fma(b0, b0, zeB); zeB = fma(b1, b1, zeB);
        zeB = fma(b2, b2, zeB); zeB = fma(b3, b3, zeB);
#pragma unroll
        for (int k = 0; k < KC; ++k) {
            float4 c4 = *(const float4*)(cbs + k * DSEG + j * 4);  // broadcast
            double c0 = (double)c4.x, c1 = (double)c4.y;
            double c2 = (double)c4.z, c3 = (double)c4.w;
            double a = dotA[k];
            a = fma(a0, c0, a); a = fma(a1, c1, a);
            a = fma(a2, c2, a); a = fma(a3, c3, a);
            dotA[k] = a;
            double b = dotB[k];
            b = fma(b0, c0, b); b = fma(b1, c1, b);
            b = fma(b2, c2, b); b = fma(b3, c3, b);
            dotB[k] = b;
        }
    }

    // ---- Cross-wave reduction, two rounds; partials alias the codebook ----
    __syncthreads();  // all waves finished reading cbl
    double* part = arena;
    const double* c2s = c2d + s * KC;  // 128 B, scalar loads
    double loss_acc = 0.0;             // meaningful on wave0 lane0

    // ===== round A (tokens tok_base + lane) =====
    if (w != 0) {
        double* p = part + ((w - 1) * 64 + lane) * (KC + 1);
#pragma unroll
        for (int k = 0; k < KC; ++k) p[k] = dotA[k];
        p[KC] = zeA;
    }
    __syncthreads();
    if (w == 0) {
#pragma unroll
        for (int c = 0; c < 3; ++c) {
            const double* p = part + (c * 64 + lane) * (KC + 1);
#pragma unroll
            for (int k = 0; k < KC; ++k) dotA[k] += p[k];
            zeA += p[KC];
        }
        // argmin; strict < keeps lowest k (jnp.argmin first-index tie-break)
        double best = c2s[0] - 2.0 * dotA[0];
        int bk = 0;
#pragma unroll
        for (int k = 1; k < KC; ++k) {
            double sc = c2s[k] - 2.0 * dotA[k];
            if (sc < best) { best = sc; bk = k; }
        }
        ids_lds[lane] = bk;
        atomicAdd(&ids_out[tokA], (float)(bk << (4 * s)));
        double mind = zeA + best;
#pragma unroll
        for (int off = 32; off > 0; off >>= 1)
            mind += __shfl_down(mind, off, 64);
        loss_acc = mind;
    }
    __syncthreads();  // round-A partial buffer free

    // ===== round B (tokens tok_base + 64 + lane) =====
    if (w != 0) {
        double* p = part + ((w - 1) * 64 + lane) * (KC + 1);
#pragma unroll
        for (int k = 0; k < KC; ++k) p[k] = dotB[k];
        p[KC] = zeB;
    }
    __syncthreads();
    if (w == 0) {
#pragma unroll
        for (int c = 0; c < 3; ++c) {
            const double* p = part + (c * 64 + lane) * (KC + 1);
#pragma unroll
            for (int k = 0; k < KC; ++k) dotB[k] += p[k];
            zeB += p[KC];
        }
        double best = c2s[0] - 2.0 * dotB[0];
        int bk = 0;
#pragma unroll
        for (int k = 1; k < KC; ++k) {
            double sc = c2s[k] - 2.0 * dotB[k];
            if (sc < best) { best = sc; bk = k; }
        }
        ids_lds[64 + lane] = bk;
        atomicAdd(&ids_out[tokB], (float)(bk << (4 * s)));
        double mind = zeB + best;
#pragma unroll
        for (int off = 32; off > 0; off >>= 1)
            mind += __shfl_down(mind, off, 64);
        if (lane == 0)
            atomicAdd(loss_out, (float)((loss_acc + mind) * (1.25 / 8388608.0)));
    }
    __syncthreads();  // ids_lds visible to all waves

    // ---- Phase 2: z write, 32 rows per wave, coalesced 1KB per row-seg ----
    const float4* cbf4 = (const float4*)cb;
#pragma unroll 4
    for (int r0 = 0; r0 < 32; ++r0) {
        int r = ch * 32 + r0;
        int k = ids_lds[r];  // wave-uniform
        float4 v = cbf4[(s * KC + k) * (DSEG / 4) + lane];
        ((float4*)(z_out + (tok_base + r) * D_FULL + (long)s * DSEG))[lane] = v;
    }
}

extern "C" void kernel_launch(void* const* d_in, const int* in_sizes, int n_in,
                              void* d_out, int out_size, void* d_ws, size_t ws_size,
                              hipStream_t stream) {
    const float* h  = (const float*)d_in[0];
    const float* cb = (const float*)d_in[1];

    const int n_h = in_sizes[0];          // 33554432
    const int tokens = n_h / D_FULL;      // 32768

    float* z_out    = (float*)d_out;
    float* ids_out  = z_out + (size_t)n_h;
    float* loss_out = ids_out + tokens;

    double* c2d = (double*)d_ws;          // 64 doubles

    dvq_prep<<<64, 256, 0, stream>>>(cb, c2d, ids_out, loss_out);
    dvq_main<<<(tokens / 128) * SEG, 256, 0, stream>>>(h, cb, c2d, z_out,
                                                       ids_out, loss_out);
}